// Round 7
// baseline (988.756 us; speedup 1.0000x reference)
//
#include <hip/hip_runtime.h>

#define Bn 64
#define Sn 512
#define Hn 1024
#define Tn 67

#define LOG2E 1.4426950408889634f
#define LN2   0.6931471805599453f

// ---------------------------------------------------------------------------
// Kernel 1: em = leaky_relu(hidden, 0.01) @ W + b  (unchanged, frozen)
// ---------------------------------------------------------------------------
__global__ __launch_bounds__(256) void gemm_em(
    const float* __restrict__ hidden, const float* __restrict__ W,
    const float* __restrict__ bias, float* __restrict__ em,
    float* __restrict__ out)
{
    __shared__ __align__(16) float hs[64][36];
    __shared__ __align__(16) float wt[80][36];

    const int tid = threadIdx.x;
    const int tx = tid & 15, ty = tid >> 4;
    const int row0 = blockIdx.x * 64;

    if (blockIdx.x == 0 && tid == 0) out[0] = 0.0f;

    float acc[4][5];
#pragma unroll
    for (int u = 0; u < 4; ++u)
#pragma unroll
        for (int v = 0; v < 5; ++v) acc[u][v] = 0.f;

    for (int kc = 0; kc < Hn; kc += 32) {
#pragma unroll
        for (int l = 0; l < 2; ++l) {
            int idx = tid + l * 256;
            int r = idx >> 3, kq = (idx & 7) << 2;
            float4 v = *reinterpret_cast<const float4*>(
                &hidden[(size_t)(row0 + r) * Hn + kc + kq]);
            v.x = v.x > 0.f ? v.x : 0.01f * v.x;
            v.y = v.y > 0.f ? v.y : 0.01f * v.y;
            v.z = v.z > 0.f ? v.z : 0.01f * v.z;
            v.w = v.w > 0.f ? v.w : 0.01f * v.w;
            *reinterpret_cast<float4*>(&hs[r][kq]) = v;
        }
        for (int idx = tid; idx < 32 * Tn; idx += 256) {
            int k = idx / Tn;
            int t = idx - k * Tn;
            wt[t][k] = W[(size_t)(kc + k) * Tn + t];
        }
        __syncthreads();

#pragma unroll
        for (int k0 = 0; k0 < 32; k0 += 4) {
            float4 hv[4], wv[5];
#pragma unroll
            for (int u = 0; u < 4; ++u)
                hv[u] = *reinterpret_cast<float4*>(&hs[ty + 16 * u][k0]);
#pragma unroll
            for (int v = 0; v < 5; ++v)
                wv[v] = *reinterpret_cast<float4*>(&wt[tx + 16 * v][k0]);
#pragma unroll
            for (int u = 0; u < 4; ++u)
#pragma unroll
                for (int v = 0; v < 5; ++v) {
                    acc[u][v] = fmaf(hv[u].x, wv[v].x, acc[u][v]);
                    acc[u][v] = fmaf(hv[u].y, wv[v].y, acc[u][v]);
                    acc[u][v] = fmaf(hv[u].z, wv[v].z, acc[u][v]);
                    acc[u][v] = fmaf(hv[u].w, wv[v].w, acc[u][v]);
                }
        }
        __syncthreads();
    }

#pragma unroll
    for (int v = 0; v < 5; ++v) {
        int c = tx + 16 * v;
        if (c < Tn) {
            float bb = bias[c];
#pragma unroll
            for (int u = 0; u < 4; ++u) {
                int row = row0 + ty + 16 * u;
                em[(size_t)row * Tn + c] = acc[u][v] + bb;
            }
        }
    }
}

// ---------------------------------------------------------------------------
// first-index-tie-break max over 68 candidates c_i = V[i] + T[i]
// ---------------------------------------------------------------------------
__device__ __forceinline__ void tmax68_add(const float4* Vp, const float* T,
                                           float& bv, int& bi)
{
    float bvv[34]; int bx[34];
#pragma unroll
    for (int q = 0; q < 17; ++q) {
        float4 v = Vp[q];
        float c0 = v.x + T[4 * q + 0];
        float c1 = v.y + T[4 * q + 1];
        float c2 = v.z + T[4 * q + 2];
        float c3 = v.w + T[4 * q + 3];
        bool r0 = c1 > c0;
        bvv[2 * q]     = r0 ? c1 : c0;
        bx[2 * q]      = r0 ? 4 * q + 1 : 4 * q + 0;
        bool r1 = c3 > c2;
        bvv[2 * q + 1] = r1 ? c3 : c2;
        bx[2 * q + 1]  = r1 ? 4 * q + 3 : 4 * q + 2;
    }
#pragma unroll
    for (int q = 0; q < 17; ++q) {
        bool r = bvv[2 * q + 1] > bvv[2 * q];
        bvv[q] = r ? bvv[2 * q + 1] : bvv[2 * q];
        bx[q]  = r ? bx[2 * q + 1]  : bx[2 * q];
    }
#pragma unroll
    for (int q = 0; q < 8; ++q) {
        bool r = bvv[2 * q + 1] > bvv[2 * q];
        bvv[q] = r ? bvv[2 * q + 1] : bvv[2 * q];
        bx[q]  = r ? bx[2 * q + 1]  : bx[2 * q];
    }
    bvv[8] = bvv[16]; bx[8] = bx[16];
#pragma unroll
    for (int q = 0; q < 4; ++q) {
        bool r = bvv[2 * q + 1] > bvv[2 * q];
        bvv[q] = r ? bvv[2 * q + 1] : bvv[2 * q];
        bx[q]  = r ? bx[2 * q + 1]  : bx[2 * q];
    }
    bvv[4] = bvv[8]; bx[4] = bx[8];
#pragma unroll
    for (int q = 0; q < 2; ++q) {
        bool r = bvv[2 * q + 1] > bvv[2 * q];
        bvv[q] = r ? bvv[2 * q + 1] : bvv[2 * q];
        bx[q]  = r ? bx[2 * q + 1]  : bx[2 * q];
    }
    bvv[2] = bvv[4]; bx[2] = bx[4];
    { bool r = bvv[1] > bvv[0]; bvv[0] = r ? bvv[1] : bvv[0]; bx[0] = r ? bx[1] : bx[0]; }
    { bool r = bvv[2] > bvv[0]; bvv[0] = r ? bvv[2] : bvv[0]; bx[0] = r ? bx[2] : bx[0]; }
    bv = bvv[0]; bi = bx[0];
}

// same, candidates are the LDS values directly
__device__ __forceinline__ void tmax68_plain(const float4* Vp, float& bv, int& bi)
{
    float bvv[34]; int bx[34];
#pragma unroll
    for (int q = 0; q < 17; ++q) {
        float4 v = Vp[q];
        bool r0 = v.y > v.x;
        bvv[2 * q]     = r0 ? v.y : v.x;
        bx[2 * q]      = r0 ? 4 * q + 1 : 4 * q + 0;
        bool r1 = v.w > v.z;
        bvv[2 * q + 1] = r1 ? v.w : v.z;
        bx[2 * q + 1]  = r1 ? 4 * q + 3 : 4 * q + 2;
    }
#pragma unroll
    for (int q = 0; q < 17; ++q) {
        bool r = bvv[2 * q + 1] > bvv[2 * q];
        bvv[q] = r ? bvv[2 * q + 1] : bvv[2 * q];
        bx[q]  = r ? bx[2 * q + 1]  : bx[2 * q];
    }
#pragma unroll
    for (int q = 0; q < 8; ++q) {
        bool r = bvv[2 * q + 1] > bvv[2 * q];
        bvv[q] = r ? bvv[2 * q + 1] : bvv[2 * q];
        bx[q]  = r ? bx[2 * q + 1]  : bx[2 * q];
    }
    bvv[8] = bvv[16]; bx[8] = bx[16];
#pragma unroll
    for (int q = 0; q < 4; ++q) {
        bool r = bvv[2 * q + 1] > bvv[2 * q];
        bvv[q] = r ? bvv[2 * q + 1] : bvv[2 * q];
        bx[q]  = r ? bx[2 * q + 1]  : bx[2 * q];
    }
    bvv[4] = bvv[8]; bx[4] = bx[8];
#pragma unroll
    for (int q = 0; q < 2; ++q) {
        bool r = bvv[2 * q + 1] > bvv[2 * q];
        bvv[q] = r ? bvv[2 * q + 1] : bvv[2 * q];
        bx[q]  = r ? bx[2 * q + 1]  : bx[2 * q];
    }
    bvv[2] = bvv[4]; bx[2] = bx[4];
    { bool r = bvv[1] > bvv[0]; bvv[0] = r ? bvv[1] : bvv[0]; bx[0] = r ? bx[1] : bx[0]; }
    { bool r = bvv[2] > bvv[0]; bvv[0] = r ? bvv[2] : bvv[0]; bx[0] = r ? bx[2] : bx[0]; }
    bv = bvv[0]; bi = bx[0];
}

// ---------------------------------------------------------------------------
// Kernel 2: barrier-free scans, register-resident tables. 64 blocks x 192 thr.
// wave0 = CRF: Ec1[68] in VGPRs; states 64-66 via LDS contribution-sum;
//         reference max M̂ replicated (M̂ += log2(sum p)*ln2) - no shuffles.
// wave1 = Viterbi: Tc1[68] in VGPRs; states 64-66 via LDS candidate array +
//         plain tournament (bit-exact values, first-index ties).
// wave2 = numerator. One __syncthreads per wave (loss combine).
// ---------------------------------------------------------------------------
__global__ __launch_bounds__(192) void crf_scan4(
    const float* __restrict__ em, const int* __restrict__ labels,
    const int* __restrict__ mask, const float* __restrict__ startT,
    const float* __restrict__ endT, const float* __restrict__ trans,
    float* __restrict__ out)
{
    __shared__ __align__(16) float emC[2][1088];   // 16 rows x 68
    __shared__ __align__(16) float emV[2][1088];
    __shared__ int maskC[Sn];
    __shared__ int maskV[Sn];
    __shared__ __align__(16) float pb[2][72];      // CRF p state
    __shared__ __align__(16) float gC[2][3][72];   // CRF contributions to 64..66
    __shared__ __align__(16) float vb[2][72];      // Viterbi scores
    __shared__ __align__(16) float gV[2][3][72];   // Viterbi candidates to 64..66
    __shared__ unsigned char hist[Sn - 1][68];
    __shared__ int tg[Sn];
    __shared__ float numSh;
    __shared__ int lenSh;

    const int tid = threadIdx.x;
    const int wid = tid >> 6;
    const int lane = tid & 63;
    const int b = blockIdx.x;
    const float* emg = em + (size_t)b * Sn * Tn;
    const int u2 = lane < 3 ? lane : 2;
    const int st2 = 64 + u2;

    if (wid == 0) {
        // ================= CRF wave =================
#pragma unroll
        for (int i = 0; i < 8; ++i)
            maskC[lane + i * 64] = mask[b * Sn + lane + i * 64];

        float Ec1[68];
#pragma unroll
        for (int i = 0; i < Tn; ++i) Ec1[i] = exp2f(trans[i * Tn + lane] * LOG2E);
        Ec1[67] = 0.f;
        float Esf[3], Ess[3];
#pragma unroll
        for (int u = 0; u < 3; ++u) {
            Esf[u] = exp2f(trans[lane * Tn + 64 + u] * LOG2E);
            Ess[u] = exp2f(trans[st2 * Tn + 64 + u] * LOG2E);
        }

        float sreg[17];
#pragma unroll
        for (int i = 0; i < 17; ++i) { int idx = lane + i * 64; if (idx > 1071) idx = 1071; sreg[i] = emg[idx]; }
#pragma unroll
        for (int i = 0; i < 17; ++i) {
            int idx = lane + i * 64;
            if (idx < 1072) { int s = idx / 67; emC[0][s * 68 + (idx - s * 67)] = sreg[i]; }
        }
#pragma unroll
        for (int i = 0; i < 17; ++i) { int idx = lane + i * 64; if (idx > 1071) idx = 1071; sreg[i] = emg[1072 + idx]; }

        if (lane == 0) {
            pb[0][67] = 0.f; pb[1][67] = 0.f;
#pragma unroll
            for (int u = 0; u < 3; ++u) { gC[0][u][67] = 0.f; gC[1][u][67] = 0.f; }
        }

        // init t = 0
        float sc1 = startT[lane] + emC[0][lane];
        float sc2 = startT[st2] + emC[0][st2];
        float M = startT[0] + emC[0][0];          // uniform across lanes
        float p1 = exp2f((sc1 - M) * LOG2E);
        float p2 = exp2f((sc2 - M) * LOG2E);
        pb[0][lane] = p1;
        if (lane < 3) pb[0][64 + lane] = p2;
#pragma unroll
        for (int u = 0; u < 3; ++u) gC[0][u][lane] = p1 * Esf[u];
        if (lane < 3) {
#pragma unroll
            for (int v = 0; v < 3; ++v) gC[0][v][64 + lane] = p2 * Ess[v];
        }

        for (int t = 1; t < Sn; ++t) {
            const int cb = (t >> 4) & 1;
            if ((t & 15) == 0) {
                const int k = t >> 4;
#pragma unroll
                for (int i = 0; i < 17; ++i) {
                    int idx = lane + i * 64;
                    if (idx < 1072) { int s = idx / 67; emC[cb][s * 68 + (idx - s * 67)] = sreg[i]; }
                }
                if (k < 31) {
                    const float* src = emg + (size_t)(k + 1) * 1072;
#pragma unroll
                    for (int i = 0; i < 17; ++i) { int idx = lane + i * 64; if (idx > 1071) idx = 1071; sreg[i] = src[idx]; }
                }
            }
            const int pv = (t + 1) & 1, cu = t & 1;
            const float* row = &emC[cb][(t & 15) * 68];
            float em1 = row[lane];
            float em2 = row[st2];
            int m = maskC[t];

            const float4* P = (const float4*)&pb[pv][0];
            float a0 = 0, a1 = 0, a2 = 0, a3 = 0;
            float s0 = 0, s1s = 0, s2s = 0, s3 = 0;
#pragma unroll
            for (int q = 0; q < 17; ++q) {
                float4 pvv = P[q];
                a0 = fmaf(pvv.x, Ec1[4 * q + 0], a0);
                a1 = fmaf(pvv.y, Ec1[4 * q + 1], a1);
                a2 = fmaf(pvv.z, Ec1[4 * q + 2], a2);
                a3 = fmaf(pvv.w, Ec1[4 * q + 3], a3);
                s0 += pvv.x; s1s += pvv.y; s2s += pvv.z; s3 += pvv.w;
            }
            float aa1 = (a0 + a1) + (a2 + a3);
            float S = (s0 + s1s) + (s2s + s3);

            // secondary dot for lanes 0-2 (contribution sum, any order ok)
            const float4* G = (const float4*)&gC[pv][u2][0];
            float g0 = 0, g1 = 0, g2 = 0, g3 = 0;
#pragma unroll
            for (int q = 0; q < 17; ++q) {
                float4 gv = G[q];
                g0 += gv.x; g1 += gv.y; g2 += gv.z; g3 += gv.w;
            }
            float aa2 = (g0 + g1) + (g2 + g3);

            float n1 = M + log2f(aa1) * LN2 + em1;
            float n2 = M + log2f(aa2) * LN2 + em2;
            if (m) { sc1 = n1; sc2 = n2; }
            M = M + log2f(S) * LN2;               // new reference (uniform)
            p1 = exp2f((sc1 - M) * LOG2E);
            p2 = exp2f((sc2 - M) * LOG2E);
            pb[cu][lane] = p1;
            if (lane < 3) pb[cu][64 + lane] = p2;
#pragma unroll
            for (int u = 0; u < 3; ++u) gC[cu][u][lane] = p1 * Esf[u];
            if (lane < 3) {
#pragma unroll
                for (int v = 0; v < 3; ++v) gC[cu][v][64 + lane] = p2 * Ess[v];
            }
        }

        // denominator
        float* F = &pb[0][0];
        F[lane] = sc1 + endT[lane];
        if (lane < 3) F[64 + lane] = sc2 + endT[64 + lane];
        if (lane == 0) F[67] = -1e30f;
        float mx = -1e30f;
        const float4* Fv = (const float4*)F;
#pragma unroll
        for (int q = 0; q < 17; ++q) {
            float4 v = Fv[q];
            mx = fmaxf(mx, fmaxf(fmaxf(v.x, v.y), fmaxf(v.z, v.w)));
        }
        float ss = 0.f;
#pragma unroll
        for (int q = 0; q < 17; ++q) {
            float4 v = Fv[q];
            ss += exp2f((v.x - mx) * LOG2E) + exp2f((v.y - mx) * LOG2E)
                + exp2f((v.z - mx) * LOG2E) + exp2f((v.w - mx) * LOG2E);
        }
        float denom = mx + log2f(ss) * LN2;
        __syncthreads();
        if (lane == 0) {
            int len = lenSh;
            float num = numSh + endT[labels[b * Sn + len - 1]];
            atomicAdd(out, -(num - denom) * (1.0f / (float)Bn));
        }
    } else if (wid == 1) {
        // ================= Viterbi wave =================
#pragma unroll
        for (int i = 0; i < 8; ++i)
            maskV[lane + i * 64] = mask[b * Sn + lane + i * 64];

        float Tc1[68];
#pragma unroll
        for (int i = 0; i < Tn; ++i) Tc1[i] = trans[i * Tn + lane];
        Tc1[67] = 0.f;
        float Tsf[3], Tss[3];
#pragma unroll
        for (int u = 0; u < 3; ++u) {
            Tsf[u] = trans[lane * Tn + 64 + u];
            Tss[u] = trans[st2 * Tn + 64 + u];
        }

        float sreg[17];
#pragma unroll
        for (int i = 0; i < 17; ++i) { int idx = lane + i * 64; if (idx > 1071) idx = 1071; sreg[i] = emg[idx]; }
#pragma unroll
        for (int i = 0; i < 17; ++i) {
            int idx = lane + i * 64;
            if (idx < 1072) { int s = idx / 67; emV[0][s * 68 + (idx - s * 67)] = sreg[i]; }
        }
#pragma unroll
        for (int i = 0; i < 17; ++i) { int idx = lane + i * 64; if (idx > 1071) idx = 1071; sreg[i] = emg[1072 + idx]; }

        if (lane == 0) {
            vb[0][67] = -1e30f; vb[1][67] = -1e30f;
#pragma unroll
            for (int u = 0; u < 3; ++u) { gV[0][u][67] = -1e30f; gV[1][u][67] = -1e30f; }
        }

        float sc1 = startT[lane] + emV[0][lane];
        float sc2 = startT[st2] + emV[0][st2];
        vb[0][lane] = sc1;
        if (lane < 3) vb[0][64 + lane] = sc2;
#pragma unroll
        for (int u = 0; u < 3; ++u) gV[0][u][lane] = sc1 + Tsf[u];
        if (lane < 3) {
#pragma unroll
            for (int v = 0; v < 3; ++v) gV[0][v][64 + lane] = sc2 + Tss[v];
        }

        for (int t = 1; t < Sn; ++t) {
            const int cb = (t >> 4) & 1;
            if ((t & 15) == 0) {
                const int k = t >> 4;
#pragma unroll
                for (int i = 0; i < 17; ++i) {
                    int idx = lane + i * 64;
                    if (idx < 1072) { int s = idx / 67; emV[cb][s * 68 + (idx - s * 67)] = sreg[i]; }
                }
                if (k < 31) {
                    const float* src = emg + (size_t)(k + 1) * 1072;
#pragma unroll
                    for (int i = 0; i < 17; ++i) { int idx = lane + i * 64; if (idx > 1071) idx = 1071; sreg[i] = src[idx]; }
                }
            }
            const int pv = (t + 1) & 1, cu = t & 1;
            const float* row = &emV[cb][(t & 15) * 68];
            float em1 = row[lane];
            float em2 = row[st2];
            int m = maskV[t];

            float bv1; int bi1;
            tmax68_add((const float4*)&vb[pv][0], Tc1, bv1, bi1);
            float n1 = bv1 + em1;

            float bv2; int bi2;
            tmax68_plain((const float4*)&gV[pv][u2][0], bv2, bi2);
            float n2 = bv2 + em2;

            int idx1 = m ? bi1 : lane;
            int idx2 = m ? bi2 : st2;
            if (m) { sc1 = n1; sc2 = n2; }

            hist[t - 1][lane] = (unsigned char)idx1;
            vb[cu][lane] = sc1;
#pragma unroll
            for (int u = 0; u < 3; ++u) gV[cu][u][lane] = sc1 + Tsf[u];
            if (lane < 3) {
                hist[t - 1][64 + lane] = (unsigned char)idx2;
                vb[cu][64 + lane] = sc2;
#pragma unroll
                for (int v = 0; v < 3; ++v) gV[cu][v][64 + lane] = sc2 + Tss[v];
            }
        }

        // final argmax over score + endT (first index)
        float* F = &vb[0][0];
        F[lane] = sc1 + endT[lane];
        if (lane < 3) F[64 + lane] = sc2 + endT[64 + lane];
        if (lane == 0) F[67] = -1e30f;
        float bvf; int bif;
        tmax68_plain((const float4*)F, bvf, bif);

        if (lane == 0) {
            int carry = bif;
            tg[Sn - 1] = carry;
            for (int k = Sn - 2; k >= 0; --k) {
                carry = hist[k][carry];
                tg[k] = carry;
            }
        }
        float* tagsOut = out + 1 + b * Sn;
#pragma unroll
        for (int i = 0; i < 8; ++i) {
            int s = lane + i * 64;
            tagsOut[s] = maskV[s] ? (float)tg[s] : 0.f;
        }
        __syncthreads();
    } else {
        // ================= numerator wave =================
        float part = 0.f; int lenp = 0;
#pragma unroll
        for (int i = 0; i < 8; ++i) {
            int s = lane + i * 64;
            int ms = mask[b * Sn + s];
            lenp += ms;
            int ls = labels[b * Sn + s];
            if (s == 0) {
                part += startT[ls] + emg[ls];
            } else if (ms) {
                int lp = labels[b * Sn + s - 1];
                part += trans[lp * Tn + ls] + emg[(size_t)s * Tn + ls];
            }
        }
#pragma unroll
        for (int k = 1; k < 64; k <<= 1) {
            part += __shfl_xor(part, k);
            lenp += __shfl_xor(lenp, k);
        }
        if (lane == 0) { numSh = part; lenSh = lenp; }
        __syncthreads();
    }
}

extern "C" void kernel_launch(void* const* d_in, const int* in_sizes, int n_in,
                              void* d_out, int out_size, void* d_ws, size_t ws_size,
                              hipStream_t stream) {
    const float* hidden = (const float*)d_in[0];
    const int*   labels = (const int*)d_in[1];
    const int*   maskp  = (const int*)d_in[2];
    const float* W      = (const float*)d_in[3];
    const float* bias   = (const float*)d_in[4];
    const float* startT = (const float*)d_in[5];
    const float* endT   = (const float*)d_in[6];
    const float* trans  = (const float*)d_in[7];
    float* out = (float*)d_out;
    float* em  = out + 1 + (size_t)Bn * Sn;

    hipLaunchKernelGGL(gemm_em, dim3((Bn * Sn) / 64), dim3(256), 0, stream,
                       hidden, W, bias, em, out);
    hipLaunchKernelGGL(crf_scan4, dim3(Bn), dim3(192), 0, stream,
                       em, labels, maskp, startT, endT, trans, out);
}

// Round 8
// 789.274 us; speedup vs baseline: 1.2527x; 1.2527x over previous
//
#include <hip/hip_runtime.h>

#define Bn 64
#define Sn 512
#define Hn 1024
#define Tn 67

#define LOG2E 1.4426950408889634f
#define LN2   0.6931471805599453f

// ---------------------------------------------------------------------------
// Kernel 1: em = leaky_relu(hidden, 0.01) @ W + b  (unchanged, frozen)
// ---------------------------------------------------------------------------
__global__ __launch_bounds__(256) void gemm_em(
    const float* __restrict__ hidden, const float* __restrict__ W,
    const float* __restrict__ bias, float* __restrict__ em,
    float* __restrict__ out)
{
    __shared__ __align__(16) float hs[64][36];
    __shared__ __align__(16) float wt[80][36];

    const int tid = threadIdx.x;
    const int tx = tid & 15, ty = tid >> 4;
    const int row0 = blockIdx.x * 64;

    if (blockIdx.x == 0 && tid == 0) out[0] = 0.0f;

    float acc[4][5];
#pragma unroll
    for (int u = 0; u < 4; ++u)
#pragma unroll
        for (int v = 0; v < 5; ++v) acc[u][v] = 0.f;

    for (int kc = 0; kc < Hn; kc += 32) {
#pragma unroll
        for (int l = 0; l < 2; ++l) {
            int idx = tid + l * 256;
            int r = idx >> 3, kq = (idx & 7) << 2;
            float4 v = *reinterpret_cast<const float4*>(
                &hidden[(size_t)(row0 + r) * Hn + kc + kq]);
            v.x = v.x > 0.f ? v.x : 0.01f * v.x;
            v.y = v.y > 0.f ? v.y : 0.01f * v.y;
            v.z = v.z > 0.f ? v.z : 0.01f * v.z;
            v.w = v.w > 0.f ? v.w : 0.01f * v.w;
            *reinterpret_cast<float4*>(&hs[r][kq]) = v;
        }
        for (int idx = tid; idx < 32 * Tn; idx += 256) {
            int k = idx / Tn;
            int t = idx - k * Tn;
            wt[t][k] = W[(size_t)(kc + k) * Tn + t];
        }
        __syncthreads();

#pragma unroll
        for (int k0 = 0; k0 < 32; k0 += 4) {
            float4 hv[4], wv[5];
#pragma unroll
            for (int u = 0; u < 4; ++u)
                hv[u] = *reinterpret_cast<float4*>(&hs[ty + 16 * u][k0]);
#pragma unroll
            for (int v = 0; v < 5; ++v)
                wv[v] = *reinterpret_cast<float4*>(&wt[tx + 16 * v][k0]);
#pragma unroll
            for (int u = 0; u < 4; ++u)
#pragma unroll
                for (int v = 0; v < 5; ++v) {
                    acc[u][v] = fmaf(hv[u].x, wv[v].x, acc[u][v]);
                    acc[u][v] = fmaf(hv[u].y, wv[v].y, acc[u][v]);
                    acc[u][v] = fmaf(hv[u].z, wv[v].z, acc[u][v]);
                    acc[u][v] = fmaf(hv[u].w, wv[v].w, acc[u][v]);
                }
        }
        __syncthreads();
    }

#pragma unroll
    for (int v = 0; v < 5; ++v) {
        int c = tx + 16 * v;
        if (c < Tn) {
            float bb = bias[c];
#pragma unroll
            for (int u = 0; u < 4; ++u) {
                int row = row0 + ty + 16 * u;
                em[(size_t)row * Tn + c] = acc[u][v] + bb;
            }
        }
    }
}

// ---------------------------------------------------------------------------
// Kernel 2: barrier-free per-batch scans. 64 blocks x 192 threads (3 waves).
// IDENTICAL structure to round 6 (passed correctness); ONE change:
// __launch_bounds__(192, 1) -> min 1 wave/EU -> full VGPR budget, so the
// 68-entry transition tables promote to registers instead of scratch.
// ---------------------------------------------------------------------------
__device__ __forceinline__ unsigned long long shflx64(unsigned long long v, int m) {
    unsigned int lo = (unsigned int)v, hi = (unsigned int)(v >> 32);
    lo = __shfl_xor(lo, m);
    hi = __shfl_xor(hi, m);
    return ((unsigned long long)hi << 32) | lo;
}

__device__ __forceinline__ unsigned long long packkey(float v, int idx) {
    unsigned int b = __float_as_uint(v);
    unsigned int s = b ^ (unsigned int)(((int)b >> 31) | 0x80000000);
    return ((unsigned long long)s << 32) | (unsigned int)(127 - idx);
}

__device__ __forceinline__ float unpackval(unsigned long long key) {
    unsigned int s = (unsigned int)(key >> 32);
    unsigned int b = s ^ (unsigned int)((~(int)s >> 31) | 0x80000000);
    return __uint_as_float(b);
}

__global__ __launch_bounds__(192, 1) void crf_scan5(
    const float* __restrict__ em, const int* __restrict__ labels,
    const int* __restrict__ mask, const float* __restrict__ startT,
    const float* __restrict__ endT, const float* __restrict__ trans,
    float* __restrict__ out)
{
    __shared__ __align__(16) float emC[2][1088];   // 16 rows x 68, CRF wave
    __shared__ __align__(16) float emV[2][1088];   // Viterbi wave
    __shared__ int maskC[Sn];
    __shared__ int maskV[Sn];
    __shared__ __align__(16) float pb[2][72];
    __shared__ __align__(16) float vb[2][72];
    __shared__ unsigned char hist[Sn - 1][68];
    __shared__ int tg[Sn];
    __shared__ float numSh;
    __shared__ int lenSh;

    const int tid = threadIdx.x;
    const int wid = tid >> 6;
    const int lane = tid & 63;
    const int b = blockIdx.x;
    const float* emg = em + (size_t)b * Sn * Tn;
    const int u2 = lane < 3 ? lane : 2;
    const int st2 = 64 + u2;

    if (wid == 0) {
        // ================= CRF wave =================
#pragma unroll
        for (int i = 0; i < 8; ++i)
            maskC[lane + i * 64] = mask[b * Sn + lane + i * 64];

        float Ec1[68], Ec2[68];
#pragma unroll
        for (int i = 0; i < Tn; ++i) {
            Ec1[i] = exp2f(trans[i * Tn + lane] * LOG2E);
            Ec2[i] = exp2f(trans[i * Tn + st2] * LOG2E);
        }
        Ec1[67] = 0.f; Ec2[67] = 0.f;

        float sreg[17];
#pragma unroll
        for (int i = 0; i < 17; ++i) { int idx = lane + i * 64; if (idx > 1071) idx = 1071; sreg[i] = emg[idx]; }
#pragma unroll
        for (int i = 0; i < 17; ++i) {
            int idx = lane + i * 64;
            if (idx < 1072) { int s = idx / 67; emC[0][s * 68 + (idx - s * 67)] = sreg[i]; }
        }
#pragma unroll
        for (int i = 0; i < 17; ++i) { int idx = lane + i * 64; if (idx > 1071) idx = 1071; sreg[i] = emg[1072 + idx]; }

        if (lane == 0) { pb[0][67] = 0.f; pb[1][67] = 0.f; }

        float sc1 = startT[lane] + emC[0][lane];
        float sc2 = startT[st2] + emC[0][st2];
        float M = __shfl(sc1, 0);
        float p1 = exp2f((sc1 - M) * LOG2E);
        float p2 = exp2f((sc2 - M) * LOG2E);
        pb[0][lane] = p1;
        if (lane < 3) pb[0][64 + lane] = p2;
        float Mprev = M;

        for (int t = 1; t < Sn; ++t) {
            const int cb = (t >> 4) & 1;
            if ((t & 15) == 0) {
                const int k = t >> 4;
#pragma unroll
                for (int i = 0; i < 17; ++i) {
                    int idx = lane + i * 64;
                    if (idx < 1072) { int s = idx / 67; emC[cb][s * 68 + (idx - s * 67)] = sreg[i]; }
                }
                if (k < 31) {
                    const float* src = emg + (size_t)(k + 1) * 1072;
#pragma unroll
                    for (int i = 0; i < 17; ++i) { int idx = lane + i * 64; if (idx > 1071) idx = 1071; sreg[i] = src[idx]; }
                }
            }
            const float* row = &emC[cb][(t & 15) * 68];
            float em1 = row[lane];
            float em2 = row[st2];
            int m = maskC[t];
            const float4* P = (const float4*)&pb[(t + 1) & 1][0];
            float a0 = 0, a1 = 0, a2 = 0, a3 = 0, c0 = 0, c1 = 0, c2 = 0, c3 = 0;
#pragma unroll
            for (int q = 0; q < 17; ++q) {
                float4 pv = P[q];
                a0 = fmaf(pv.x, Ec1[4 * q + 0], a0); c0 = fmaf(pv.x, Ec2[4 * q + 0], c0);
                a1 = fmaf(pv.y, Ec1[4 * q + 1], a1); c1 = fmaf(pv.y, Ec2[4 * q + 1], c1);
                a2 = fmaf(pv.z, Ec1[4 * q + 2], a2); c2 = fmaf(pv.z, Ec2[4 * q + 2], c2);
                a3 = fmaf(pv.w, Ec1[4 * q + 3], a3); c3 = fmaf(pv.w, Ec2[4 * q + 3], c3);
            }
            float s1 = (a0 + a1) + (a2 + a3);
            float s2 = (c0 + c1) + (c2 + c3);
            float n1 = Mprev + log2f(s1) * LN2 + em1;
            float n2 = Mprev + log2f(s2) * LN2 + em2;
            if (m) { sc1 = n1; sc2 = n2; }
            M = __shfl(sc1, 0);
            p1 = exp2f((sc1 - M) * LOG2E);
            p2 = exp2f((sc2 - M) * LOG2E);
            float* Wp = &pb[t & 1][0];
            Wp[lane] = p1;
            if (lane < 3) Wp[64 + lane] = p2;
            Mprev = M;
        }

        // denominator (wave-wide redundant reduce)
        float* F = &pb[0][0];
        F[lane] = sc1 + endT[lane];
        if (lane < 3) F[64 + lane] = sc2 + endT[64 + lane];
        if (lane == 0) F[67] = -1e30f;
        float mx = -1e30f;
        const float4* Fv = (const float4*)F;
#pragma unroll
        for (int q = 0; q < 17; ++q) {
            float4 v = Fv[q];
            mx = fmaxf(mx, fmaxf(fmaxf(v.x, v.y), fmaxf(v.z, v.w)));
        }
        float ss = 0.f;
#pragma unroll
        for (int q = 0; q < 17; ++q) {
            float4 v = Fv[q];
            ss += exp2f((v.x - mx) * LOG2E) + exp2f((v.y - mx) * LOG2E)
                + exp2f((v.z - mx) * LOG2E) + exp2f((v.w - mx) * LOG2E);
        }
        float denom = mx + log2f(ss) * LN2;
        __syncthreads();
        if (lane == 0) {
            int len = lenSh;
            float num = numSh + endT[labels[b * Sn + len - 1]];
            atomicAdd(out, -(num - denom) * (1.0f / (float)Bn));
        }
    } else if (wid == 1) {
        // ================= Viterbi wave =================
#pragma unroll
        for (int i = 0; i < 8; ++i)
            maskV[lane + i * 64] = mask[b * Sn + lane + i * 64];

        float Tc1[68];
#pragma unroll
        for (int i = 0; i < Tn; ++i) Tc1[i] = trans[i * Tn + lane];
        Tc1[67] = 0.f;
        float Tsf[3], Tss[3];
        const int rsec = (lane < 3) ? (64 + lane) : 0;
#pragma unroll
        for (int u = 0; u < 3; ++u) {
            Tsf[u] = trans[lane * Tn + 64 + u];
            Tss[u] = trans[rsec * Tn + 64 + u];
        }

        float sreg[17];
#pragma unroll
        for (int i = 0; i < 17; ++i) { int idx = lane + i * 64; if (idx > 1071) idx = 1071; sreg[i] = emg[idx]; }
#pragma unroll
        for (int i = 0; i < 17; ++i) {
            int idx = lane + i * 64;
            if (idx < 1072) { int s = idx / 67; emV[0][s * 68 + (idx - s * 67)] = sreg[i]; }
        }
#pragma unroll
        for (int i = 0; i < 17; ++i) { int idx = lane + i * 64; if (idx > 1071) idx = 1071; sreg[i] = emg[1072 + idx]; }

        float sc1 = startT[lane] + emV[0][lane];
        float sc2 = startT[st2] + emV[0][st2];
        vb[0][lane] = sc1;
        if (lane < 3) vb[0][64 + lane] = sc2;
        if (lane == 0) { vb[0][67] = -1e30f; vb[1][67] = -1e30f; }

        for (int t = 1; t < Sn; ++t) {
            const int cb = (t >> 4) & 1;
            if ((t & 15) == 0) {
                const int k = t >> 4;
#pragma unroll
                for (int i = 0; i < 17; ++i) {
                    int idx = lane + i * 64;
                    if (idx < 1072) { int s = idx / 67; emV[cb][s * 68 + (idx - s * 67)] = sreg[i]; }
                }
                if (k < 31) {
                    const float* src = emg + (size_t)(k + 1) * 1072;
#pragma unroll
                    for (int i = 0; i < 17; ++i) { int idx = lane + i * 64; if (idx > 1071) idx = 1071; sreg[i] = src[idx]; }
                }
            }
            const float* row = &emV[cb][(t & 15) * 68];
            float em1 = row[lane];
            float e64 = row[64], e65 = row[65], e66 = row[66];
            int m = maskV[t];

            // ---- primary target (lane) tournament over 68 sources ----
            const float4* Vp = (const float4*)&vb[(t + 1) & 1][0];
            float bvv[34]; int bx[34];
#pragma unroll
            for (int q = 0; q < 17; ++q) {
                float4 v = Vp[q];
                float c0 = v.x + Tc1[4 * q + 0];
                float c1 = v.y + Tc1[4 * q + 1];
                float c2 = v.z + Tc1[4 * q + 2];
                float c3 = v.w + Tc1[4 * q + 3];
                bool r0 = c1 > c0;
                bvv[2 * q]     = r0 ? c1 : c0;
                bx[2 * q]      = r0 ? 4 * q + 1 : 4 * q + 0;
                bool r1 = c3 > c2;
                bvv[2 * q + 1] = r1 ? c3 : c2;
                bx[2 * q + 1]  = r1 ? 4 * q + 3 : 4 * q + 2;
            }
#pragma unroll
            for (int q = 0; q < 17; ++q) {
                bool r = bvv[2 * q + 1] > bvv[2 * q];
                bvv[q] = r ? bvv[2 * q + 1] : bvv[2 * q];
                bx[q]  = r ? bx[2 * q + 1]  : bx[2 * q];
            }
#pragma unroll
            for (int q = 0; q < 8; ++q) {
                bool r = bvv[2 * q + 1] > bvv[2 * q];
                bvv[q] = r ? bvv[2 * q + 1] : bvv[2 * q];
                bx[q]  = r ? bx[2 * q + 1]  : bx[2 * q];
            }
            bvv[8] = bvv[16]; bx[8] = bx[16];
#pragma unroll
            for (int q = 0; q < 4; ++q) {
                bool r = bvv[2 * q + 1] > bvv[2 * q];
                bvv[q] = r ? bvv[2 * q + 1] : bvv[2 * q];
                bx[q]  = r ? bx[2 * q + 1]  : bx[2 * q];
            }
            bvv[4] = bvv[8]; bx[4] = bx[8];
#pragma unroll
            for (int q = 0; q < 2; ++q) {
                bool r = bvv[2 * q + 1] > bvv[2 * q];
                bvv[q] = r ? bvv[2 * q + 1] : bvv[2 * q];
                bx[q]  = r ? bx[2 * q + 1]  : bx[2 * q];
            }
            bvv[2] = bvv[4]; bx[2] = bx[4];
            { bool r = bvv[1] > bvv[0]; bvv[0] = r ? bvv[1] : bvv[0]; bx[0] = r ? bx[1] : bx[0]; }
            { bool r = bvv[2] > bvv[0]; bvv[0] = r ? bvv[2] : bvv[0]; bx[0] = r ? bx[2] : bx[0]; }
            float n1 = bvv[0] + em1;

            // ---- targets 64..66 via u64-key shuffle reduce (exact ties) ----
            float ca = sc1 + Tsf[0]; int ia = lane;
            float cbv = sc1 + Tsf[1]; int ib = lane;
            float cc = sc1 + Tsf[2]; int ic = lane;
            if (lane < 3) {
                float sa = sc2 + Tss[0]; if (sa > ca)  { ca = sa;  ia = 64 + lane; }
                float sb = sc2 + Tss[1]; if (sb > cbv) { cbv = sb; ib = 64 + lane; }
                float scv = sc2 + Tss[2]; if (scv > cc) { cc = scv; ic = 64 + lane; }
            }
            unsigned long long k0 = packkey(ca, ia);
            unsigned long long k1 = packkey(cbv, ib);
            unsigned long long k2 = packkey(cc, ic);
#pragma unroll
            for (int k = 1; k < 64; k <<= 1) {
                unsigned long long o0 = shflx64(k0, k); if (o0 > k0) k0 = o0;
                unsigned long long o1 = shflx64(k1, k); if (o1 > k1) k1 = o1;
                unsigned long long o2 = shflx64(k2, k); if (o2 > k2) k2 = o2;
            }
            float v64 = unpackval(k0) + e64;
            float v65 = unpackval(k1) + e65;
            float v66 = unpackval(k2) + e66;
            int i64 = 127 - (int)(unsigned int)(k0 & 0xffffffffu);
            int i65 = 127 - (int)(unsigned int)(k1 & 0xffffffffu);
            int i66 = 127 - (int)(unsigned int)(k2 & 0xffffffffu);

            float nuv = (lane == 0) ? v64 : (lane == 1) ? v65 : v66;
            int nui = (lane == 0) ? i64 : (lane == 1) ? i65 : i66;

            int idx1 = m ? bx[0] : lane;
            int idx2 = m ? nui : st2;
            if (m) { sc1 = n1; sc2 = nuv; }

            hist[t - 1][lane] = (unsigned char)idx1;
            float* Wv = &vb[t & 1][0];
            Wv[lane] = sc1;
            if (lane < 3) {
                hist[t - 1][64 + lane] = (unsigned char)idx2;
                Wv[64 + lane] = sc2;
            }
        }

        // ---- final argmax (first index) over score + endT ----
        float* F = &vb[0][0];
        F[lane] = sc1 + endT[lane];
        if (lane < 3) F[64 + lane] = sc2 + endT[64 + lane];
        if (lane == 0) F[67] = -1e30f;
        const float4* Fv = (const float4*)F;
        float bvv[34]; int bx[34];
#pragma unroll
        for (int q = 0; q < 17; ++q) {
            float4 v = Fv[q];
            bool r0 = v.y > v.x;
            bvv[2 * q]     = r0 ? v.y : v.x;
            bx[2 * q]      = r0 ? 4 * q + 1 : 4 * q + 0;
            bool r1 = v.w > v.z;
            bvv[2 * q + 1] = r1 ? v.w : v.z;
            bx[2 * q + 1]  = r1 ? 4 * q + 3 : 4 * q + 2;
        }
#pragma unroll
        for (int q = 0; q < 17; ++q) {
            bool r = bvv[2 * q + 1] > bvv[2 * q];
            bvv[q] = r ? bvv[2 * q + 1] : bvv[2 * q];
            bx[q]  = r ? bx[2 * q + 1]  : bx[2 * q];
        }
#pragma unroll
        for (int q = 0; q < 8; ++q) {
            bool r = bvv[2 * q + 1] > bvv[2 * q];
            bvv[q] = r ? bvv[2 * q + 1] : bvv[2 * q];
            bx[q]  = r ? bx[2 * q + 1]  : bx[2 * q];
        }
        bvv[8] = bvv[16]; bx[8] = bx[16];
#pragma unroll
        for (int q = 0; q < 4; ++q) {
            bool r = bvv[2 * q + 1] > bvv[2 * q];
            bvv[q] = r ? bvv[2 * q + 1] : bvv[2 * q];
            bx[q]  = r ? bx[2 * q + 1]  : bx[2 * q];
        }
        bvv[4] = bvv[8]; bx[4] = bx[8];
#pragma unroll
        for (int q = 0; q < 2; ++q) {
            bool r = bvv[2 * q + 1] > bvv[2 * q];
            bvv[q] = r ? bvv[2 * q + 1] : bvv[2 * q];
            bx[q]  = r ? bx[2 * q + 1]  : bx[2 * q];
        }
        bvv[2] = bvv[4]; bx[2] = bx[4];
        { bool r = bvv[1] > bvv[0]; bvv[0] = r ? bvv[1] : bvv[0]; bx[0] = r ? bx[1] : bx[0]; }
        { bool r = bvv[2] > bvv[0]; bvv[0] = r ? bvv[2] : bvv[0]; bx[0] = r ? bx[2] : bx[0]; }

        if (lane == 0) {
            int carry = bx[0];
            tg[Sn - 1] = carry;
            for (int k = Sn - 2; k >= 0; --k) {
                carry = hist[k][carry];
                tg[k] = carry;
            }
        }
        float* tagsOut = out + 1 + b * Sn;
#pragma unroll
        for (int i = 0; i < 8; ++i) {
            int s = lane + i * 64;
            tagsOut[s] = maskV[s] ? (float)tg[s] : 0.f;
        }
        __syncthreads();
    } else {
        // ================= numerator wave =================
        float part = 0.f; int lenp = 0;
#pragma unroll
        for (int i = 0; i < 8; ++i) {
            int s = lane + i * 64;
            int ms = mask[b * Sn + s];
            lenp += ms;
            int ls = labels[b * Sn + s];
            if (s == 0) {
                part += startT[ls] + emg[ls];
            } else if (ms) {
                int lp = labels[b * Sn + s - 1];
                part += trans[lp * Tn + ls] + emg[(size_t)s * Tn + ls];
            }
        }
#pragma unroll
        for (int k = 1; k < 64; k <<= 1) {
            part += __shfl_xor(part, k);
            lenp += __shfl_xor(lenp, k);
        }
        if (lane == 0) { numSh = part; lenSh = lenp; }
        __syncthreads();
    }
}

extern "C" void kernel_launch(void* const* d_in, const int* in_sizes, int n_in,
                              void* d_out, int out_size, void* d_ws, size_t ws_size,
                              hipStream_t stream) {
    const float* hidden = (const float*)d_in[0];
    const int*   labels = (const int*)d_in[1];
    const int*   maskp  = (const int*)d_in[2];
    const float* W      = (const float*)d_in[3];
    const float* bias   = (const float*)d_in[4];
    const float* startT = (const float*)d_in[5];
    const float* endT   = (const float*)d_in[6];
    const float* trans  = (const float*)d_in[7];
    float* out = (float*)d_out;
    float* em  = out + 1 + (size_t)Bn * Sn;

    hipLaunchKernelGGL(gemm_em, dim3((Bn * Sn) / 64), dim3(256), 0, stream,
                       hidden, W, bias, em, out);
    hipLaunchKernelGGL(crf_scan5, dim3(Bn), dim3(192), 0, stream,
                       em, labels, maskp, startT, endT, trans, out);
}